// Round 1
// baseline (202.763 us; speedup 1.0000x reference)
//
#include <hip/hip_runtime.h>
#include <climits>

#define EMB 128
#define EMB2 256

// ---------------------------------------------------------------------------
// Kernel A: weff[k] = sum_j Wo[0,128+j] * Wq[j,k]  (k in [0,256))
// Also initializes the qmin slot to INT_MAX (d_ws is poisoned each call).
// ---------------------------------------------------------------------------
__global__ void prep_weights_kernel(const float* __restrict__ Wq,
                                    const float* __restrict__ Wo,
                                    float* __restrict__ weff,
                                    int* __restrict__ qmin) {
    int k = threadIdx.x;  // 256 threads
    float acc = 0.f;
#pragma unroll 8
    for (int j = 0; j < EMB; ++j)
        acc += Wo[EMB + j] * Wq[j * EMB2 + k];
    weff[k] = acc;
    if (k == 0) *qmin = INT_MAX;
}

// ---------------------------------------------------------------------------
// Kernel B: qmin = min over edges of max(edge_index[0,e], edge_index[1,e])
// ---------------------------------------------------------------------------
__global__ void qmin_kernel(const int* __restrict__ ei, int E,
                            int* __restrict__ qmin) {
    int m = INT_MAX;
    int stride = gridDim.x * blockDim.x;
    for (int e = blockIdx.x * blockDim.x + threadIdx.x; e < E; e += stride) {
        int a = ei[e];
        int b = ei[e + E];
        int mx = a > b ? a : b;
        m = mx < m ? mx : m;
    }
    // wave (64-lane) reduce
    for (int off = 32; off; off >>= 1) {
        int o = __shfl_down(m, off, 64);
        m = o < m ? o : m;
    }
    __shared__ int sm[8];
    int wid = threadIdx.x >> 6;
    if ((threadIdx.x & 63) == 0) sm[wid] = m;
    __syncthreads();
    if (threadIdx.x == 0) {
        int nw = blockDim.x >> 6;
        int r = sm[0];
        for (int w = 1; w < nw; ++w) r = sm[w] < r ? sm[w] : r;
        atomicMin(qmin, r);
    }
}

// ---------------------------------------------------------------------------
// Kernel C: per-node dot products. One 64-lane wave per node (grid-stride).
//   d1[i] = Wo[0,0:128]   . z[i]
//   d2[i] = weff[0:128]   . z[i]
//   d3[i] = weff[128:256] . z0[i]
// Each lane handles 2 consecutive floats (float2) -> 512B coalesced per row.
// ---------------------------------------------------------------------------
__global__ void node_dots_kernel(const float* __restrict__ z,
                                 const float* __restrict__ z0,
                                 const float* __restrict__ Wo,
                                 const float* __restrict__ weff,
                                 float* __restrict__ d1,
                                 float* __restrict__ d2,
                                 float* __restrict__ d3,
                                 int N) {
    int gtid = blockIdx.x * blockDim.x + threadIdx.x;
    int wave = gtid >> 6;
    int lane = gtid & 63;
    int nwaves = (gridDim.x * blockDim.x) >> 6;

    float2 w1 = ((const float2*)Wo)[lane];         // Wo[0, 2*lane : 2*lane+2]
    float2 wa = ((const float2*)weff)[lane];       // weff[0:128] slice
    float2 wb = ((const float2*)weff)[64 + lane];  // weff[128:256] slice

    for (int i = wave; i < N; i += nwaves) {
        float2 zv  = ((const float2*)(z  + (size_t)i * EMB))[lane];
        float2 z0v = ((const float2*)(z0 + (size_t)i * EMB))[lane];
        float p1 = w1.x * zv.x + w1.y * zv.y;
        float p2 = wa.x * zv.x + wa.y * zv.y;
        float p3 = wb.x * z0v.x + wb.y * z0v.y;
        for (int off = 32; off; off >>= 1) {
            p1 += __shfl_down(p1, off, 64);
            p2 += __shfl_down(p2, off, 64);
            p3 += __shfl_down(p3, off, 64);
        }
        if (lane == 0) {
            d1[i] = p1;
            d2[i] = p2;
            d3[i] = p3;
        }
    }
}

// ---------------------------------------------------------------------------
// Kernel D: per-edge combine.
//   out[e] = d1[e0] + d2[e1] + d3[max(e0,e1)-qmin] + bo
// d1/d2/d3 are 400 KB each -> L2-resident gathers.
// ---------------------------------------------------------------------------
__global__ void edge_out_kernel(const int* __restrict__ ei,
                                const float* __restrict__ d1,
                                const float* __restrict__ d2,
                                const float* __restrict__ d3,
                                const int* __restrict__ qminp,
                                const float* __restrict__ bo,
                                float* __restrict__ out, int E) {
    int qmin = *qminp;
    float b0 = *bo;
    int stride = gridDim.x * blockDim.x;
    for (int e = blockIdx.x * blockDim.x + threadIdx.x; e < E; e += stride) {
        int a = ei[e];
        int b = ei[e + E];
        int q = (a > b ? a : b) - qmin;
        out[e] = d1[a] + d2[b] + d3[q] + b0;
    }
}

extern "C" void kernel_launch(void* const* d_in, const int* in_sizes, int n_in,
                              void* d_out, int out_size, void* d_ws, size_t ws_size,
                              hipStream_t stream) {
    const float* z    = (const float*)d_in[0];
    const int*   ei   = (const int*)d_in[1];
    const float* z0   = (const float*)d_in[2];
    const float* Wq   = (const float*)d_in[3];
    const float* Wo   = (const float*)d_in[4];
    const float* bo   = (const float*)d_in[5];
    float* out = (float*)d_out;

    int N = in_sizes[0] / EMB;   // 100000
    int E = in_sizes[1] / 2;     // 1000000

    // Workspace layout: d1[N] | d2[N] | d3[N] | weff[256] | qmin (int)
    float* ws   = (float*)d_ws;
    float* d1   = ws;
    float* d2   = ws + N;
    float* d3   = ws + 2 * (size_t)N;
    float* weff = ws + 3 * (size_t)N;
    int*   qmin = (int*)(weff + EMB2);

    // A: fold Wo2 into Wq -> weff (also init qmin slot)
    prep_weights_kernel<<<1, EMB2, 0, stream>>>(Wq, Wo, weff, qmin);

    // B: global min of per-edge max id
    qmin_kernel<<<256, 256, 0, stream>>>(ei, E, qmin);

    // C: per-node dots (one wave per node, grid-stride)
    node_dots_kernel<<<512, 256, 0, stream>>>(z, z0, Wo, weff, d1, d2, d3, N);

    // D: per-edge combine
    int blocksD = (E + 255) / 256;
    if (blocksD > 8192) blocksD = 8192;
    edge_out_kernel<<<blocksD, 256, 0, stream>>>(ei, d1, d2, d3, qmin, bo, out, E);
}

// Round 2
// 158.616 us; speedup vs baseline: 1.2783x; 1.2783x over previous
//
#include <hip/hip_runtime.h>
#include <climits>

#define EMB 128
#define EMB2 256

// ---------------------------------------------------------------------------
// Kernel A: weff[k] = sum_j Wo[0,128+j] * Wq[j,k]  (k in [0,256))
// Also initializes the qmin slot to INT_MAX (d_ws is poisoned each call).
// ---------------------------------------------------------------------------
__global__ void prep_weights_kernel(const float* __restrict__ Wq,
                                    const float* __restrict__ Wo,
                                    float* __restrict__ weff,
                                    int* __restrict__ qmin) {
    int k = threadIdx.x;  // 256 threads
    float acc = 0.f;
#pragma unroll 8
    for (int j = 0; j < EMB; ++j)
        acc += Wo[EMB + j] * Wq[j * EMB2 + k];
    weff[k] = acc;
    if (k == 0) *qmin = INT_MAX;
}

// ---------------------------------------------------------------------------
// Kernel B: qmin = min over edges of max(edge_index[0,e], edge_index[1,e])
// int4-vectorized, grid-stride; per-wave shuffle reduce then one atomic/block.
// ---------------------------------------------------------------------------
__global__ void qmin_kernel(const int* __restrict__ ei, int E,
                            int* __restrict__ qmin) {
    int m = INT_MAX;
    int nvec = E >> 2;  // E assumed large; tail handled below
    int stride = gridDim.x * blockDim.x;
    const int4* r0 = (const int4*)ei;
    const int4* r1 = (const int4*)(ei + E);
    for (int v = blockIdx.x * blockDim.x + threadIdx.x; v < nvec; v += stride) {
        int4 a = r0[v];
        int4 b = r1[v];
        int m0 = max(a.x, b.x), m1 = max(a.y, b.y);
        int m2 = max(a.z, b.z), m3 = max(a.w, b.w);
        m = min(m, min(min(m0, m1), min(m2, m3)));
    }
    // tail
    if (blockIdx.x == 0 && threadIdx.x < (E & 3)) {
        int e = (nvec << 2) + threadIdx.x;
        m = min(m, max(ei[e], ei[e + E]));
    }
    for (int off = 32; off; off >>= 1)
        m = min(m, __shfl_xor(m, off, 64));
    __shared__ int sm[8];
    int wid = threadIdx.x >> 6;
    if ((threadIdx.x & 63) == 0) sm[wid] = m;
    __syncthreads();
    if (threadIdx.x == 0) {
        int nw = blockDim.x >> 6;
        int r = sm[0];
        for (int w = 1; w < nw; ++w) r = min(r, sm[w]);
        atomicMin(qmin, r);
    }
}

// ---------------------------------------------------------------------------
// Kernel C: per-node dot products -> packed float4 table.
//   tab[i] = { Wo[0,0:128].z[i], weff[0:128].z[i], weff[128:256].z0[i], 0 }
// 2 rows per wave: lane = 32*sub + c; float4 loads (16 B/lane), 5-stage
// xor-shuffle reduce within each 32-lane half. One wave per row pair.
// ---------------------------------------------------------------------------
__global__ void node_dots_kernel(const float* __restrict__ z,
                                 const float* __restrict__ z0,
                                 const float* __restrict__ Wo,
                                 const float* __restrict__ weff,
                                 float4* __restrict__ tab,
                                 int N) {
    int gtid = blockIdx.x * blockDim.x + threadIdx.x;
    int wave = gtid >> 6;
    int lane = gtid & 63;
    int sub = lane >> 5;   // which row of the pair
    int c = lane & 31;     // column group (4 floats)
    int row = wave * 2 + sub;
    if (row >= N) return;

    float4 w1 = ((const float4*)Wo)[c];          // Wo[0, 4c:4c+4]
    float4 wa = ((const float4*)weff)[c];        // weff[0:128]
    float4 wb = ((const float4*)weff)[32 + c];   // weff[128:256]

    float4 zv  = ((const float4*)(z  + (size_t)row * EMB))[c];
    float4 z0v = ((const float4*)(z0 + (size_t)row * EMB))[c];

    float p1 = w1.x * zv.x + w1.y * zv.y + w1.z * zv.z + w1.w * zv.w;
    float p2 = wa.x * zv.x + wa.y * zv.y + wa.z * zv.z + wa.w * zv.w;
    float p3 = wb.x * z0v.x + wb.y * z0v.y + wb.z * z0v.z + wb.w * z0v.w;

#pragma unroll
    for (int off = 16; off; off >>= 1) {
        p1 += __shfl_xor(p1, off, 64);
        p2 += __shfl_xor(p2, off, 64);
        p3 += __shfl_xor(p3, off, 64);
    }
    if (c == 0) tab[row] = make_float4(p1, p2, p3, 0.f);
}

// ---------------------------------------------------------------------------
// Kernel D: per-edge combine, 4 edges/thread via int4.
//   out[e] = tab[a].x + tab[b].y + tab[max(a,b)-qmin].z + bo
// ---------------------------------------------------------------------------
__global__ void edge_out_kernel(const int* __restrict__ ei,
                                const float4* __restrict__ tab,
                                const int* __restrict__ qminp,
                                const float* __restrict__ bo,
                                float* __restrict__ out, int E) {
    int qmin = *qminp;
    float b0 = *bo;
    int t = blockIdx.x * blockDim.x + threadIdx.x;
    int e4 = t << 2;
    if (e4 + 3 < E) {
        int4 a = *(const int4*)(ei + e4);
        int4 b = *(const int4*)(ei + E + e4);
        float4 r;
        r.x = tab[a.x].x + tab[b.x].y + tab[max(a.x, b.x) - qmin].z + b0;
        r.y = tab[a.y].x + tab[b.y].y + tab[max(a.y, b.y) - qmin].z + b0;
        r.z = tab[a.z].x + tab[b.z].y + tab[max(a.z, b.z) - qmin].z + b0;
        r.w = tab[a.w].x + tab[b.w].y + tab[max(a.w, b.w) - qmin].z + b0;
        *(float4*)(out + e4) = r;
    } else {
        for (int e = e4; e < E; ++e) {
            int a = ei[e], b = ei[e + E];
            out[e] = tab[a].x + tab[b].y + tab[max(a, b) - qmin].z + b0;
        }
    }
}

extern "C" void kernel_launch(void* const* d_in, const int* in_sizes, int n_in,
                              void* d_out, int out_size, void* d_ws, size_t ws_size,
                              hipStream_t stream) {
    const float* z    = (const float*)d_in[0];
    const int*   ei   = (const int*)d_in[1];
    const float* z0   = (const float*)d_in[2];
    const float* Wq   = (const float*)d_in[3];
    const float* Wo   = (const float*)d_in[4];
    const float* bo   = (const float*)d_in[5];
    float* out = (float*)d_out;

    int N = in_sizes[0] / EMB;   // 100000
    int E = in_sizes[1] / 2;     // 1000000

    // Workspace layout: tab[N] (float4, 16B-aligned) | weff[256] | qmin (int)
    float4* tab = (float4*)d_ws;
    float* weff = (float*)(tab + N);
    int*   qmin = (int*)(weff + EMB2);

    // A: fold Wo2 into Wq -> weff (also init qmin slot)
    prep_weights_kernel<<<1, EMB2, 0, stream>>>(Wq, Wo, weff, qmin);

    // B: global min of per-edge max id
    qmin_kernel<<<512, 256, 0, stream>>>(ei, E, qmin);

    // C: per-node dots, one wave per row pair (4 waves/block)
    int pairs = (N + 1) / 2;
    int blocksC = (pairs + 3) / 4;   // 4 waves (= 4 pairs) per 256-thread block
    node_dots_kernel<<<blocksC, 256, 0, stream>>>(z, z0, Wo, weff, tab, N);

    // D: per-edge combine, 4 edges/thread
    int threadsD = (E + 3) / 4;
    int blocksD = (threadsD + 255) / 256;
    edge_out_kernel<<<blocksD, 256, 0, stream>>>(ei, tab, qmin, bo, out, E);
}

// Round 3
// 156.633 us; speedup vs baseline: 1.2945x; 1.0127x over previous
//
#include <hip/hip_runtime.h>
#include <climits>

#define EMB 128
#define EMB2 256

typedef float v4f __attribute__((ext_vector_type(4)));
typedef int   v4i __attribute__((ext_vector_type(4)));

// ---------------------------------------------------------------------------
// Kernel AB (fused): block 0 computes weff[k] = sum_j Wo[0,128+j]*Wq[j,k];
// blocks 1..G-1 compute qmin = min_e max(ei[0,e], ei[1,e]) via unsigned
// atomicMin (qmin slot pre-initialized to 0xFFFFFFFF by hipMemsetAsync).
// ---------------------------------------------------------------------------
__global__ void prep_kernel(const float* __restrict__ Wq,
                            const float* __restrict__ Wo,
                            const int* __restrict__ ei, int E,
                            float* __restrict__ weff,
                            unsigned int* __restrict__ qmin) {
    if (blockIdx.x == 0) {
        int k = threadIdx.x;  // 256 threads
        float acc = 0.f;
#pragma unroll 8
        for (int j = 0; j < EMB; ++j)
            acc += Wo[EMB + j] * Wq[j * EMB2 + k];
        weff[k] = acc;
        return;
    }
    unsigned int m = 0xFFFFFFFFu;
    int nvec = E >> 2;
    int nthreads = (gridDim.x - 1) * blockDim.x;
    int tid = (blockIdx.x - 1) * blockDim.x + threadIdx.x;
    const v4i* r0 = (const v4i*)ei;
    const v4i* r1 = (const v4i*)(ei + E);
    for (int v = tid; v < nvec; v += nthreads) {
        v4i a = r0[v];
        v4i b = r1[v];
        unsigned m0 = (unsigned)max(a.x, b.x), m1 = (unsigned)max(a.y, b.y);
        unsigned m2 = (unsigned)max(a.z, b.z), m3 = (unsigned)max(a.w, b.w);
        m = min(m, min(min(m0, m1), min(m2, m3)));
    }
    if (blockIdx.x == 1 && threadIdx.x < (E & 3)) {  // tail
        int e = (nvec << 2) + threadIdx.x;
        m = min(m, (unsigned)max(ei[e], ei[e + E]));
    }
    for (int off = 32; off; off >>= 1) {
        unsigned o = (unsigned)__shfl_xor((int)m, off, 64);
        m = min(m, o);
    }
    __shared__ unsigned sm[4];
    int wid = threadIdx.x >> 6;
    if ((threadIdx.x & 63) == 0) sm[wid] = m;
    __syncthreads();
    if (threadIdx.x == 0) {
        unsigned r = min(min(sm[0], sm[1]), min(sm[2], sm[3]));
        atomicMin(qmin, r);
    }
}

// ---------------------------------------------------------------------------
// Kernel C: per-node dot products -> packed float4 table.
//   tab[i] = { Wo[0,0:128].z[i], weff[0:128].z[i], weff[128:256].z0[i], 0 }
// 2 rows per wave (32 lanes x float4 = 512B/row); non-temporal loads so the
// 102 MB read-once stream doesn't evict tab/ei from L2 before kernel D.
// ---------------------------------------------------------------------------
__global__ void node_dots_kernel(const float* __restrict__ z,
                                 const float* __restrict__ z0,
                                 const float* __restrict__ Wo,
                                 const float* __restrict__ weff,
                                 v4f* __restrict__ tab,
                                 int N) {
    int gtid = blockIdx.x * blockDim.x + threadIdx.x;
    int wave = gtid >> 6;
    int lane = gtid & 63;
    int sub = lane >> 5;   // which row of the pair
    int c = lane & 31;     // column group (4 floats)
    int row = wave * 2 + sub;
    if (row >= N) return;

    v4f w1 = ((const v4f*)Wo)[c];          // Wo[0, 4c:4c+4]
    v4f wa = ((const v4f*)weff)[c];        // weff[0:128]
    v4f wb = ((const v4f*)weff)[32 + c];   // weff[128:256]

    v4f zv  = __builtin_nontemporal_load(((const v4f*)(z  + (size_t)row * EMB)) + c);
    v4f z0v = __builtin_nontemporal_load(((const v4f*)(z0 + (size_t)row * EMB)) + c);

    float p1 = w1.x * zv.x + w1.y * zv.y + w1.z * zv.z + w1.w * zv.w;
    float p2 = wa.x * zv.x + wa.y * zv.y + wa.z * zv.z + wa.w * zv.w;
    float p3 = wb.x * z0v.x + wb.y * z0v.y + wb.z * z0v.z + wb.w * z0v.w;

#pragma unroll
    for (int off = 16; off; off >>= 1) {
        p1 += __shfl_xor(p1, off, 64);
        p2 += __shfl_xor(p2, off, 64);
        p3 += __shfl_xor(p3, off, 64);
    }
    if (c == 0) {
        v4f r; r.x = p1; r.y = p2; r.z = p3; r.w = 0.f;
        tab[row] = r;
    }
}

// ---------------------------------------------------------------------------
// Kernel D: per-edge combine, 4 edges/thread via int4.
//   out[e] = tab[a].x + tab[b].y + tab[max(a,b)-qmin].z + bo
// tab is 1.6 MB -> L2-resident gathers (<=2 distinct lines/edge since the
// .z gather shares a line with a or b). Non-temporal store for out.
// ---------------------------------------------------------------------------
__global__ void edge_out_kernel(const int* __restrict__ ei,
                                const v4f* __restrict__ tab,
                                const int* __restrict__ qminp,
                                const float* __restrict__ bo,
                                float* __restrict__ out, int E) {
    int qmin = *qminp;
    float b0 = *bo;
    int t = blockIdx.x * blockDim.x + threadIdx.x;
    int e4 = t << 2;
    if (e4 + 3 < E) {
        v4i a = *(const v4i*)(ei + e4);
        v4i b = *(const v4i*)(ei + E + e4);
        v4f r;
        r.x = tab[a.x].x + tab[b.x].y + tab[max(a.x, b.x) - qmin].z + b0;
        r.y = tab[a.y].x + tab[b.y].y + tab[max(a.y, b.y) - qmin].z + b0;
        r.z = tab[a.z].x + tab[b.z].y + tab[max(a.z, b.z) - qmin].z + b0;
        r.w = tab[a.w].x + tab[b.w].y + tab[max(a.w, b.w) - qmin].z + b0;
        __builtin_nontemporal_store(r, (v4f*)(out + e4));
    } else {
        for (int e = e4; e < E; ++e) {
            int a = ei[e], b = ei[e + E];
            out[e] = tab[a].x + tab[b].y + tab[max(a, b) - qmin].z + b0;
        }
    }
}

extern "C" void kernel_launch(void* const* d_in, const int* in_sizes, int n_in,
                              void* d_out, int out_size, void* d_ws, size_t ws_size,
                              hipStream_t stream) {
    const float* z    = (const float*)d_in[0];
    const int*   ei   = (const int*)d_in[1];
    const float* z0   = (const float*)d_in[2];
    const float* Wq   = (const float*)d_in[3];
    const float* Wo   = (const float*)d_in[4];
    const float* bo   = (const float*)d_in[5];
    float* out = (float*)d_out;

    int N = in_sizes[0] / EMB;   // 100000
    int E = in_sizes[1] / 2;     // 1000000

    // Workspace layout: tab[N] (float4, 16B-aligned) | weff[256] | qmin (u32)
    v4f* tab = (v4f*)d_ws;
    float* weff = (float*)(tab + N);
    unsigned int* qmin = (unsigned int*)(weff + EMB2);

    // Init qmin slot to 0xFFFFFFFF (async memset is graph-capturable)
    hipMemsetAsync(qmin, 0xFF, sizeof(unsigned int), stream);

    // AB: weff (block 0) + qmin reduction (blocks 1..512)
    prep_kernel<<<513, 256, 0, stream>>>(Wq, Wo, ei, E, weff, qmin);

    // C: per-node dots, one wave per row pair (4 waves/block)
    int pairs = (N + 1) / 2;
    int blocksC = (pairs + 3) / 4;
    node_dots_kernel<<<blocksC, 256, 0, stream>>>(z, z0, Wo, weff, tab, N);

    // D: per-edge combine, 4 edges/thread
    int threadsD = (E + 3) / 4;
    int blocksD = (threadsD + 255) / 256;
    edge_out_kernel<<<blocksD, 256, 0, stream>>>(ei, tab, (const int*)qmin, bo, out, E);
}